// Round 2
// baseline (3304.885 us; speedup 1.0000x reference)
//
#include <hip/hip_runtime.h>
#include <hip/hip_bf16.h>
#include <math.h>

#define L_DIM 4096
#define H_DIM 512
#define B_DIM 8

__device__ __forceinline__ float bf_lo(unsigned v) { return __uint_as_float(v << 16); }
__device__ __forceinline__ float bf_hi(unsigned v) { return __uint_as_float(v & 0xffff0000u); }
__device__ __forceinline__ unsigned f2bf(float f) {
    unsigned x = __float_as_uint(f);
    return (x + 0x7fffu + ((x >> 16) & 1u)) >> 16;   // RNE, finite inputs only
}

__device__ __forceinline__ void bf8_to_f8(uint4 v, float* dst) {
    dst[0] = bf_lo(v.x); dst[1] = bf_hi(v.x);
    dst[2] = bf_lo(v.y); dst[3] = bf_hi(v.y);
    dst[4] = bf_lo(v.z); dst[5] = bf_hi(v.z);
    dst[6] = bf_lo(v.w); dst[7] = bf_hi(v.w);
}

// ---------------------------------------------------------------------------
// Stage 1: causal conv (Toeplitz) + D-skip + exact GELU, per (h, b).
// y[l] = sum_{m<=l} u[m] * k[l-m] + u[l]*D[h];  g = gelu(y) stored bf16.
// Block = 256 threads, each thread owns 16 consecutive l values.
// k is staged with a 16-float zero apron so negative k-indices read 0
// (handles both zero-padding and causality with NO branches).
// ---------------------------------------------------------------------------
__global__ __launch_bounds__(256) void conv_gelu(
    const float* __restrict__ u,    // (B,H,L) fp32
    const float* __restrict__ kk,   // (C=1,H,L) fp32
    const float* __restrict__ Dp,   // (H) fp32
    unsigned short* __restrict__ g) // (B,H,L) bf16 out (workspace)
{
    __shared__ float ku_buf[16 + L_DIM];
    __shared__ float uu[L_DIM];
    float* ku = ku_buf + 16;

    const int h = blockIdx.x;
    const int b = blockIdx.y;
    const int tid = threadIdx.x;

    if (tid < 16) ku_buf[tid] = 0.0f;   // zero apron

    const float* kp = kk + h * L_DIM;
    const float* up = u + (b * H_DIM + h) * L_DIM;

    #pragma unroll
    for (int i = 0; i < 4; i++) {
        const int idx = i * 1024 + tid * 4;          // contiguous per-wave 16B loads
        *(float4*)&ku[idx] = *(const float4*)(kp + idx);
        *(float4*)&uu[idx] = *(const float4*)(up + idx);
    }
    __syncthreads();

    const float Dh = Dp[h];
    const int l0 = tid * 16;

    float acc[16];
    #pragma unroll
    for (int i = 0; i < 16; i++) acc[i] = 0.0f;

    for (int m0 = 0; m0 <= l0; m0 += 16) {
        float ub[16];
        #pragma unroll
        for (int j = 0; j < 16; j++) ub[j] = uu[m0 + j];   // wave-broadcast reads

        float kv[32];                                       // sliding k window
        const int base = l0 - m0 - 16;                      // >= -16, 16B aligned
        #pragma unroll
        for (int j = 0; j < 32; j += 4) {
            float4 t = *(const float4*)&ku[base + j];       // apron makes this safe
            kv[j] = t.x; kv[j+1] = t.y; kv[j+2] = t.z; kv[j+3] = t.w;
        }
        // 256 FMA register outer product: acc[i] += u[m0+j] * k[(l0+i)-(m0+j)]
        #pragma unroll
        for (int i = 0; i < 16; i++) {
            #pragma unroll
            for (int j = 0; j < 16; j++) {
                acc[i] = fmaf(ub[j], kv[16 + i - j], acc[i]);
            }
        }
    }

    // epilogue: skip term + exact GELU + bf16 pack + 16B stores
    unsigned w[8];
    #pragma unroll
    for (int i = 0; i < 16; i += 2) {
        float x0 = acc[i]   + uu[l0 + i]     * Dh;
        float x1 = acc[i+1] + uu[l0 + i + 1] * Dh;
        float g0 = 0.5f * x0 * (1.0f + erff(x0 * 0.70710678118654752f));
        float g1 = 0.5f * x1 * (1.0f + erff(x1 * 0.70710678118654752f));
        w[i >> 1] = f2bf(g0) | (f2bf(g1) << 16);
    }
    unsigned short* gp = g + (b * H_DIM + h) * L_DIM + l0;
    *(uint4*)(gp)     = make_uint4(w[0], w[1], w[2], w[3]);
    *(uint4*)(gp + 8) = make_uint4(w[4], w[5], w[6], w[7]);
}

// ---------------------------------------------------------------------------
// Stage 2: out[b,d,l] = sum_c W[d,c] * g[b,c,l] + bias[d]
// 64x64 output tile per block (64 d x 64 l), K staged in 64-chunks in LDS,
// 4x4 micro-tile per thread, fp32 accumulate, fp32 output.
// ---------------------------------------------------------------------------
__global__ __launch_bounds__(256) void pointwise_linear(
    const unsigned short* __restrict__ g,  // (B,H,L) bf16 (workspace)
    const float* __restrict__ W,           // (H,H) fp32 row-major [d][c]
    const float* __restrict__ bias,        // (H) fp32
    float* __restrict__ out)               // (B,H,L) fp32
{
    __shared__ float gt[64][68];   // [c][l], 68-stride: float4-aligned rows
    __shared__ float wt[64][68];   // [d][c]

    const int tid = threadIdx.x;
    const int l0 = blockIdx.x * 64;
    const int d0 = blockIdx.y * 64;
    const int b  = blockIdx.z;
    const int tx = tid & 15;       // l quad
    const int ty = tid >> 4;       // d quad

    const int lr = tid >> 2;        // staged row 0..63
    const int lc = (tid & 3) * 16;  // staged col chunk

    float acc[4][4];
    #pragma unroll
    for (int i = 0; i < 4; i++)
        #pragma unroll
        for (int j = 0; j < 4; j++) acc[i][j] = 0.0f;

    for (int c0 = 0; c0 < H_DIM; c0 += 64) {
        {
            const unsigned short* gp = g + (b * H_DIM + c0 + lr) * L_DIM + l0 + lc;
            uint4 v0 = *(const uint4*)gp;       // 8 bf16
            uint4 v1 = *(const uint4*)(gp + 8); // 8 bf16
            bf8_to_f8(v0, &gt[lr][lc]);
            bf8_to_f8(v1, &gt[lr][lc + 8]);

            const float* wp = W + (d0 + lr) * H_DIM + c0 + lc;
            #pragma unroll
            for (int q = 0; q < 4; q++)
                *(float4*)&wt[lr][lc + q * 4] = *(const float4*)(wp + q * 4);
        }
        __syncthreads();

        #pragma unroll 4
        for (int cc = 0; cc < 64; cc++) {
            float4 gv = *(const float4*)&gt[cc][tx * 4];
            float wv0 = wt[ty * 4 + 0][cc];
            float wv1 = wt[ty * 4 + 1][cc];
            float wv2 = wt[ty * 4 + 2][cc];
            float wv3 = wt[ty * 4 + 3][cc];
            acc[0][0] = fmaf(wv0, gv.x, acc[0][0]);
            acc[0][1] = fmaf(wv0, gv.y, acc[0][1]);
            acc[0][2] = fmaf(wv0, gv.z, acc[0][2]);
            acc[0][3] = fmaf(wv0, gv.w, acc[0][3]);
            acc[1][0] = fmaf(wv1, gv.x, acc[1][0]);
            acc[1][1] = fmaf(wv1, gv.y, acc[1][1]);
            acc[1][2] = fmaf(wv1, gv.z, acc[1][2]);
            acc[1][3] = fmaf(wv1, gv.w, acc[1][3]);
            acc[2][0] = fmaf(wv2, gv.x, acc[2][0]);
            acc[2][1] = fmaf(wv2, gv.y, acc[2][1]);
            acc[2][2] = fmaf(wv2, gv.z, acc[2][2]);
            acc[2][3] = fmaf(wv2, gv.w, acc[2][3]);
            acc[3][0] = fmaf(wv3, gv.x, acc[3][0]);
            acc[3][1] = fmaf(wv3, gv.y, acc[3][1]);
            acc[3][2] = fmaf(wv3, gv.z, acc[3][2]);
            acc[3][3] = fmaf(wv3, gv.w, acc[3][3]);
        }
        __syncthreads();
    }

    #pragma unroll
    for (int dq = 0; dq < 4; dq++) {
        const int d = d0 + ty * 4 + dq;
        const float bb = bias[d];
        float4 r = make_float4(acc[dq][0] + bb, acc[dq][1] + bb,
                               acc[dq][2] + bb, acc[dq][3] + bb);
        float* op = out + ((size_t)(b * H_DIM + d)) * L_DIM + l0 + tx * 4;
        *(float4*)op = r;
    }
}

extern "C" void kernel_launch(void* const* d_in, const int* in_sizes, int n_in,
                              void* d_out, int out_size, void* d_ws, size_t ws_size,
                              hipStream_t stream) {
    const float* u    = (const float*)d_in[0]; // (B,H,L)
    const float* k    = (const float*)d_in[1]; // (C,H,L) C=1
    const float* D    = (const float*)d_in[2]; // (C,H)
    const float* W    = (const float*)d_in[3]; // (H,C*H)
    const float* bias = (const float*)d_in[4]; // (H)
    float* out = (float*)d_out;
    unsigned short* g = (unsigned short*)d_ws;  // (B,H,L) bf16 intermediate, 32 MiB

    conv_gelu<<<dim3(H_DIM, B_DIM), 256, 0, stream>>>(u, k, D, g);
    pointwise_linear<<<dim3(L_DIM / 64, H_DIM / 64, B_DIM), 256, 0, stream>>>(g, W, bias, out);
}

// Round 4
// 1254.390 us; speedup vs baseline: 2.6347x; 2.6347x over previous
//
#include <hip/hip_runtime.h>
#include <hip/hip_bf16.h>
#include <math.h>

#define L_DIM 4096
#define H_DIM 512
#define B_DIM 8

__device__ __forceinline__ float bf_lo(unsigned v) { return __uint_as_float(v << 16); }
__device__ __forceinline__ float bf_hi(unsigned v) { return __uint_as_float(v & 0xffff0000u); }
__device__ __forceinline__ unsigned f2bf(float f) {
    unsigned x = __float_as_uint(f);
    return (x + 0x7fffu + ((x >> 16) & 1u)) >> 16;   // RNE, finite inputs only
}

__device__ __forceinline__ void bf8_to_f8(uint4 v, float* dst) {
    dst[0] = bf_lo(v.x); dst[1] = bf_hi(v.x);
    dst[2] = bf_lo(v.y); dst[3] = bf_hi(v.y);
    dst[4] = bf_lo(v.z); dst[5] = bf_hi(v.z);
    dst[6] = bf_lo(v.w); dst[7] = bf_hi(v.w);
}

// Padded LDS mapping for the k buffer: s(x) = x + 4*(x>>4).
// Inserts 4 pad floats per 16 → lane-to-lane stride of the sliding-window
// reads becomes 20 floats; 8 consecutive lanes then cover all 32 banks
// exactly once (gcd(20,32)=4, b128 spans 4 banks) → conflict-free.
// x%16==0 window starts keep every float4 inside one 16-group, s stays
// 16B-aligned, and the zero apron x in [0,16) maps to itself.
// constexpr so it can size the __shared__ array (round-3 fix: was VLA).
__host__ __device__ constexpr int kpad(int x) { return x + ((x >> 4) << 2); }

// ---------------------------------------------------------------------------
// Stage 1: causal conv (Toeplitz) + D-skip + exact GELU, per (h, b).
// y[l] = sum_{m<=l} u[m] * k[l-m] + u[l]*D[h];  g = gelu(y) stored bf16.
// Block = 256 threads, each thread owns 16 consecutive l values.
// k staged with a 16-float zero apron (handles causality with NO branches)
// and the kpad() bank-conflict-free layout.
// ---------------------------------------------------------------------------
__global__ __launch_bounds__(256) void conv_gelu(
    const float* __restrict__ u,    // (B,H,L) fp32
    const float* __restrict__ kk,   // (C=1,H,L) fp32
    const float* __restrict__ Dp,   // (H) fp32
    unsigned short* __restrict__ g) // (B,H,L) bf16 out (workspace)
{
    __shared__ float pku[kpad(16 + L_DIM - 1) + 1];  // padded k, logical x in [0, 4112)
    __shared__ float uu[L_DIM];

    const int h = blockIdx.x;
    const int b = blockIdx.y;
    const int tid = threadIdx.x;

    if (tid < 16) pku[tid] = 0.0f;   // zero apron (x<16 -> s=x)

    const float* kp = kk + h * L_DIM;
    const float* up = u + (b * H_DIM + h) * L_DIM;

    #pragma unroll
    for (int i = 0; i < 4; i++) {
        const int idx = i * 1024 + tid * 4;          // contiguous per-wave 16B loads
        float4 kv4 = *(const float4*)(kp + idx);
        *(float4*)&uu[idx] = *(const float4*)(up + idx);
        *(float4*)&pku[kpad(idx + 16)] = kv4;        // float4 never crosses a 16-group
    }
    __syncthreads();

    const float Dh = Dp[h];
    const int l0 = tid * 16;

    float acc[16];
    #pragma unroll
    for (int i = 0; i < 16; i++) acc[i] = 0.0f;

    for (int m0 = 0; m0 <= l0; m0 += 16) {
        // u broadcast chunk (uniform address across the wave)
        float ub[16];
        #pragma unroll
        for (int q = 0; q < 4; q++) {
            float4 t = *(const float4*)&uu[m0 + q * 4];
            ub[q*4] = t.x; ub[q*4+1] = t.y; ub[q*4+2] = t.z; ub[q*4+3] = t.w;
        }

        // sliding k window: logical x = (l0 - m0) + 4j + t, j=0..7, t=0..3
        float kv[32];
        const int X0 = l0 - m0;                 // multiple of 16, >= 0
        #pragma unroll
        for (int j = 0; j < 8; j++) {
            float4 t = *(const float4*)&pku[kpad(X0 + 4 * j)];
            kv[j*4] = t.x; kv[j*4+1] = t.y; kv[j*4+2] = t.z; kv[j*4+3] = t.w;
        }
        // kv[n] == k[l0 - m0 - 16 + n] (negative k-index -> apron 0)
        // 256 FMA register outer product: acc[i] += u[m0+j] * k[(l0+i)-(m0+j)]
        #pragma unroll
        for (int i = 0; i < 16; i++) {
            #pragma unroll
            for (int j = 0; j < 16; j++) {
                acc[i] = fmaf(ub[j], kv[16 + i - j], acc[i]);
            }
        }
    }

    // epilogue: skip term + exact GELU + bf16 pack + 16B stores
    unsigned w[8];
    #pragma unroll
    for (int i = 0; i < 16; i += 2) {
        float x0 = acc[i]   + uu[l0 + i]     * Dh;
        float x1 = acc[i+1] + uu[l0 + i + 1] * Dh;
        float g0 = 0.5f * x0 * (1.0f + erff(x0 * 0.70710678118654752f));
        float g1 = 0.5f * x1 * (1.0f + erff(x1 * 0.70710678118654752f));
        w[i >> 1] = f2bf(g0) | (f2bf(g1) << 16);
    }
    unsigned short* gp = g + (b * H_DIM + h) * L_DIM + l0;
    *(uint4*)(gp)     = make_uint4(w[0], w[1], w[2], w[3]);
    *(uint4*)(gp + 8) = make_uint4(w[4], w[5], w[6], w[7]);
}

// ---------------------------------------------------------------------------
// Stage 2: out[b,d,l] = sum_c W[d,c] * g[b,c,l] + bias[d]
// 64x64 output tile per block, 4x4 micro-tile per thread, fp32 accumulate.
// Near the fp32 vector roofline (~120 us) — unchanged this round.
// ---------------------------------------------------------------------------
__global__ __launch_bounds__(256) void pointwise_linear(
    const unsigned short* __restrict__ g,  // (B,H,L) bf16 (workspace)
    const float* __restrict__ W,           // (H,H) fp32 row-major [d][c]
    const float* __restrict__ bias,        // (H) fp32
    float* __restrict__ out)               // (B,H,L) fp32
{
    __shared__ float gt[64][68];   // [c][l]
    __shared__ float wt[64][68];   // [d][c]

    const int tid = threadIdx.x;
    const int l0 = blockIdx.x * 64;
    const int d0 = blockIdx.y * 64;
    const int b  = blockIdx.z;
    const int tx = tid & 15;       // l quad
    const int ty = tid >> 4;       // d quad

    const int lr = tid >> 2;        // staged row 0..63
    const int lc = (tid & 3) * 16;  // staged col chunk

    float acc[4][4];
    #pragma unroll
    for (int i = 0; i < 4; i++)
        #pragma unroll
        for (int j = 0; j < 4; j++) acc[i][j] = 0.0f;

    for (int c0 = 0; c0 < H_DIM; c0 += 64) {
        {
            const unsigned short* gp = g + (b * H_DIM + c0 + lr) * L_DIM + l0 + lc;
            uint4 v0 = *(const uint4*)gp;       // 8 bf16
            uint4 v1 = *(const uint4*)(gp + 8); // 8 bf16
            bf8_to_f8(v0, &gt[lr][lc]);
            bf8_to_f8(v1, &gt[lr][lc + 8]);

            const float* wp = W + (d0 + lr) * H_DIM + c0 + lc;
            #pragma unroll
            for (int q = 0; q < 4; q++)
                *(float4*)&wt[lr][lc + q * 4] = *(const float4*)(wp + q * 4);
        }
        __syncthreads();

        #pragma unroll 4
        for (int cc = 0; cc < 64; cc++) {
            float4 gv = *(const float4*)&gt[cc][tx * 4];
            float wv0 = wt[ty * 4 + 0][cc];
            float wv1 = wt[ty * 4 + 1][cc];
            float wv2 = wt[ty * 4 + 2][cc];
            float wv3 = wt[ty * 4 + 3][cc];
            acc[0][0] = fmaf(wv0, gv.x, acc[0][0]);
            acc[0][1] = fmaf(wv0, gv.y, acc[0][1]);
            acc[0][2] = fmaf(wv0, gv.z, acc[0][2]);
            acc[0][3] = fmaf(wv0, gv.w, acc[0][3]);
            acc[1][0] = fmaf(wv1, gv.x, acc[1][0]);
            acc[1][1] = fmaf(wv1, gv.y, acc[1][1]);
            acc[1][2] = fmaf(wv1, gv.z, acc[1][2]);
            acc[1][3] = fmaf(wv1, gv.w, acc[1][3]);
            acc[2][0] = fmaf(wv2, gv.x, acc[2][0]);
            acc[2][1] = fmaf(wv2, gv.y, acc[2][1]);
            acc[2][2] = fmaf(wv2, gv.z, acc[2][2]);
            acc[2][3] = fmaf(wv2, gv.w, acc[2][3]);
            acc[3][0] = fmaf(wv3, gv.x, acc[3][0]);
            acc[3][1] = fmaf(wv3, gv.y, acc[3][1]);
            acc[3][2] = fmaf(wv3, gv.z, acc[3][2]);
            acc[3][3] = fmaf(wv3, gv.w, acc[3][3]);
        }
        __syncthreads();
    }

    #pragma unroll
    for (int dq = 0; dq < 4; dq++) {
        const int d = d0 + ty * 4 + dq;
        const float bb = bias[d];
        float4 r = make_float4(acc[dq][0] + bb, acc[dq][1] + bb,
                               acc[dq][2] + bb, acc[dq][3] + bb);
        float* op = out + ((size_t)(b * H_DIM + d)) * L_DIM + l0 + tx * 4;
        *(float4*)op = r;
    }
}

extern "C" void kernel_launch(void* const* d_in, const int* in_sizes, int n_in,
                              void* d_out, int out_size, void* d_ws, size_t ws_size,
                              hipStream_t stream) {
    const float* u    = (const float*)d_in[0]; // (B,H,L)
    const float* k    = (const float*)d_in[1]; // (C,H,L) C=1
    const float* D    = (const float*)d_in[2]; // (C,H)
    const float* W    = (const float*)d_in[3]; // (H,C*H)
    const float* bias = (const float*)d_in[4]; // (H)
    float* out = (float*)d_out;
    unsigned short* g = (unsigned short*)d_ws;  // (B,H,L) bf16 intermediate, 32 MiB

    conv_gelu<<<dim3(H_DIM, B_DIM), 256, 0, stream>>>(u, k, D, g);
    pointwise_linear<<<dim3(L_DIM / 64, H_DIM / 64, B_DIM), 256, 0, stream>>>(g, W, bias, out);
}

// Round 5
// 569.831 us; speedup vs baseline: 5.7998x; 2.2013x over previous
//
#include <hip/hip_runtime.h>
#include <hip/hip_bf16.h>
#include <math.h>

#define L_DIM 4096
#define H_DIM 512
#define B_DIM 8
#define SEG 2048

typedef __attribute__((ext_vector_type(8))) short short8;
typedef __attribute__((ext_vector_type(4))) float floatx4;

__device__ __forceinline__ float bf_lo(unsigned v) { return __uint_as_float(v << 16); }
__device__ __forceinline__ float bf_hi(unsigned v) { return __uint_as_float(v & 0xffff0000u); }
__device__ __forceinline__ unsigned f2bf(float f) {
    unsigned x = __float_as_uint(f);
    return (x + 0x7fffu + ((x >> 16) & 1u)) >> 16;   // RNE, finite inputs only
}
__device__ __forceinline__ void bf8_to_f8(uint4 v, float* dst) {
    dst[0] = bf_lo(v.x); dst[1] = bf_hi(v.x);
    dst[2] = bf_lo(v.y); dst[3] = bf_hi(v.y);
    dst[4] = bf_lo(v.z); dst[5] = bf_hi(v.z);
    dst[6] = bf_lo(v.w); dst[7] = bf_hi(v.w);
}

// ---------------------------------------------------------------------------
// Stage 1 (MFMA): causal Toeplitz conv + D-skip + exact GELU.
// Block = (h, 1024-l chunk), 256 threads = 4 waves, 8 l-pairs (32 l) per wave.
// MFMA 16x16x32 bf16: rows i = l-offset, cols n=(b, s): col (b,s) accumulates
// output tile l0+16s using m-blocks [m0+16s, m0+16s+32) — full 16-col use.
// A-frag (Toeplitz k): reversed-k LDS with 16-front/31-back zero aprons.
// Per-lane element offset parity alternates with row i -> DUAL COPY (kA at x,
// kB at x-1) so each lane's 4x ds_read_b32 is 4B-aligned, branch-free.
// B-frag (u): bf16 u staged per 2048-m segment with 32-front/48-back aprons;
// zero aprons implement causality/padding with no branches.
// ---------------------------------------------------------------------------
__global__ __launch_bounds__(256, 3) void conv_gelu_mfma(
    const float* __restrict__ u,    // (B,H,L) fp32
    const float* __restrict__ kk,   // (C=1,H,L) fp32
    const float* __restrict__ Dp,   // (H) fp32
    unsigned short* __restrict__ g) // (B,H,L) bf16 out (workspace)
{
    // kA[p] = k[L+15-p] (valid p in [16, L+15], else 0)   — krev at x+16
    // kB[p] = k[L+14-p] (valid p in [15, L+14], else 0)   — krev at x+15
    __shared__ __align__(16) unsigned short kA[4144];
    __shared__ __align__(16) unsigned short kB[4144];
    // us[b][idx] = bf16(u[b][h][ms - 32 + idx]), idx in [0,2096); row 2104 for banks
    __shared__ __align__(16) unsigned short us[8][2104];

    const int h   = blockIdx.x;
    const int Lb  = blockIdx.y << 10;        // l-chunk base
    const int tid = threadIdx.x;
    const int lane = tid & 63;
    const int w   = tid >> 6;                // wave id 0..3
    const int i   = lane & 15;               // A-row / C-col index
    const int q   = lane >> 4;               // quad
    const int b   = i & 7;                   // batch   (C-col decode)
    const int s   = i >> 3;                  // l-tile  (C-col decode)

    const float* kh = kk + (size_t)h * L_DIM;

    // ---- stage reversed k, dual copy ----
    for (int p = tid; p < 4144; p += 256) {
        int t1 = L_DIM + 15 - p;
        int t2 = L_DIM + 14 - p;
        float v1 = (t1 >= 0 && t1 < L_DIM) ? kh[t1] : 0.0f;
        float v2 = (t2 >= 0 && t2 < L_DIM) ? kh[t2] : 0.0f;
        kA[p] = (unsigned short)f2bf(v1);
        kB[p] = (unsigned short)f2bf(v2);
    }

    floatx4 acc[8];
    #pragma unroll
    for (int t = 0; t < 8; t++) acc[t] = (floatx4){0.f, 0.f, 0.f, 0.f};

    // per-lane constant pieces of the A address:
    // byte addr = 2*(L + (i odd ? 15 : 14) - i + 8q - l0 + m0), into kA (i odd) / kB (i even)
    const char* kbase = (const char*)((i & 1) ? kA : kB);
    const int aconst = 2 * (L_DIM + ((i & 1) ? 15 : 14) - i + 8 * q);

    for (int seg = 0; seg < 2; seg++) {
        const int ms = seg * SEG;
        if (seg == 1) {
            if (Lb + 992 < SEG) break;       // uniform per block: no m0 >= SEG needed
            __syncthreads();                 // protect us[] until seg-0 compute done
        }
        // ---- stage u segment (bf16), m in [ms-32, ms+2064) ----
        for (int e = tid * 4; e < 2096; e += 1024) {
            int m = ms - 32 + e;             // multiple of 4; fully in or out of range
            #pragma unroll
            for (int bb = 0; bb < 8; bb++) {
                float4 v = make_float4(0.f, 0.f, 0.f, 0.f);
                if (m >= 0 && m < L_DIM)
                    v = *(const float4*)(u + ((size_t)bb * H_DIM + h) * L_DIM + m);
                unsigned lo = f2bf(v.x) | (f2bf(v.y) << 16);
                unsigned hi = f2bf(v.z) | (f2bf(v.w) << 16);
                *(uint2*)&us[bb][e] = make_uint2(lo, hi);
            }
        }
        __syncthreads();

        // ---- K-loop ----
        const char* bbase = (const char*)&us[b][0] + 2 * (32 - ms + 16 * s + 8 * q);
        #pragma unroll
        for (int t = 0; t < 8; t++) {
            const int l0 = Lb + 32 * w + 128 * t;
            const int mstart = (seg == 0) ? -32 : ms;
            const int mend = min(l0, ms + SEG - 32);
            const char* abase = kbase + (aconst - 2 * l0);
            for (int m0 = mstart; m0 <= mend; m0 += 32) {
                const int* ap = (const int*)(abase + 2 * m0);
                union { int x[4]; short8 v; } af;
                af.x[0] = ap[0]; af.x[1] = ap[1]; af.x[2] = ap[2]; af.x[3] = ap[3];
                short8 bf = *(const short8*)(bbase + 2 * m0);
                acc[t] = __builtin_amdgcn_mfma_f32_16x16x32_bf16(af.v, bf, acc[t], 0, 0, 0);
            }
        }
    }

    // ---- epilogue: skip (fp32 u) + exact GELU + bf16 store ----
    const float Dh = Dp[h];
    #pragma unroll
    for (int t = 0; t < 8; t++) {
        const int l0 = Lb + 32 * w + 128 * t;
        const int lb2 = l0 + 16 * s + 4 * q;          // C/D: row = 4q + r, col = (b,s)
        const size_t off = ((size_t)b * H_DIM + h) * L_DIM + lb2;
        float4 uv = *(const float4*)(u + off);
        float y0 = acc[t][0] + uv.x * Dh;
        float y1 = acc[t][1] + uv.y * Dh;
        float y2 = acc[t][2] + uv.z * Dh;
        float y3 = acc[t][3] + uv.w * Dh;
        const float c = 0.70710678118654752f;
        float g0 = 0.5f * y0 * (1.0f + erff(y0 * c));
        float g1 = 0.5f * y1 * (1.0f + erff(y1 * c));
        float g2 = 0.5f * y2 * (1.0f + erff(y2 * c));
        float g3 = 0.5f * y3 * (1.0f + erff(y3 * c));
        unsigned lo = f2bf(g0) | (f2bf(g1) << 16);
        unsigned hi = f2bf(g2) | (f2bf(g3) << 16);
        *(uint2*)(g + off) = make_uint2(lo, hi);
    }
}

// ---------------------------------------------------------------------------
// Stage 2: out[b,d,l] = sum_c W[d,c] * g[b,c,l] + bias[d]   (unchanged)
// ---------------------------------------------------------------------------
__global__ __launch_bounds__(256) void pointwise_linear(
    const unsigned short* __restrict__ g,  // (B,H,L) bf16 (workspace)
    const float* __restrict__ W,           // (H,H) fp32 row-major [d][c]
    const float* __restrict__ bias,        // (H) fp32
    float* __restrict__ out)               // (B,H,L) fp32
{
    __shared__ float gt[64][68];   // [c][l]
    __shared__ float wt[64][68];   // [d][c]

    const int tid = threadIdx.x;
    const int l0 = blockIdx.x * 64;
    const int d0 = blockIdx.y * 64;
    const int b  = blockIdx.z;
    const int tx = tid & 15;       // l quad
    const int ty = tid >> 4;       // d quad

    const int lr = tid >> 2;        // staged row 0..63
    const int lc = (tid & 3) * 16;  // staged col chunk

    float acc[4][4];
    #pragma unroll
    for (int i = 0; i < 4; i++)
        #pragma unroll
        for (int j = 0; j < 4; j++) acc[i][j] = 0.0f;

    for (int c0 = 0; c0 < H_DIM; c0 += 64) {
        {
            const unsigned short* gp = g + ((size_t)b * H_DIM + c0 + lr) * L_DIM + l0 + lc;
            uint4 v0 = *(const uint4*)gp;
            uint4 v1 = *(const uint4*)(gp + 8);
            bf8_to_f8(v0, &gt[lr][lc]);
            bf8_to_f8(v1, &gt[lr][lc + 8]);

            const float* wp = W + (size_t)(d0 + lr) * H_DIM + c0 + lc;
            #pragma unroll
            for (int qq = 0; qq < 4; qq++)
                *(float4*)&wt[lr][lc + qq * 4] = *(const float4*)(wp + qq * 4);
        }
        __syncthreads();

        #pragma unroll 4
        for (int cc = 0; cc < 64; cc++) {
            float4 gv = *(const float4*)&gt[cc][tx * 4];
            float wv0 = wt[ty * 4 + 0][cc];
            float wv1 = wt[ty * 4 + 1][cc];
            float wv2 = wt[ty * 4 + 2][cc];
            float wv3 = wt[ty * 4 + 3][cc];
            acc[0][0] = fmaf(wv0, gv.x, acc[0][0]);
            acc[0][1] = fmaf(wv0, gv.y, acc[0][1]);
            acc[0][2] = fmaf(wv0, gv.z, acc[0][2]);
            acc[0][3] = fmaf(wv0, gv.w, acc[0][3]);
            acc[1][0] = fmaf(wv1, gv.x, acc[1][0]);
            acc[1][1] = fmaf(wv1, gv.y, acc[1][1]);
            acc[1][2] = fmaf(wv1, gv.z, acc[1][2]);
            acc[1][3] = fmaf(wv1, gv.w, acc[1][3]);
            acc[2][0] = fmaf(wv2, gv.x, acc[2][0]);
            acc[2][1] = fmaf(wv2, gv.y, acc[2][1]);
            acc[2][2] = fmaf(wv2, gv.z, acc[2][2]);
            acc[2][3] = fmaf(wv2, gv.w, acc[2][3]);
            acc[3][0] = fmaf(wv3, gv.x, acc[3][0]);
            acc[3][1] = fmaf(wv3, gv.y, acc[3][1]);
            acc[3][2] = fmaf(wv3, gv.z, acc[3][2]);
            acc[3][3] = fmaf(wv3, gv.w, acc[3][3]);
        }
        __syncthreads();
    }

    #pragma unroll
    for (int dq = 0; dq < 4; dq++) {
        const int d = d0 + ty * 4 + dq;
        const float bb = bias[d];
        float4 r = make_float4(acc[dq][0] + bb, acc[dq][1] + bb,
                               acc[dq][2] + bb, acc[dq][3] + bb);
        float* op = out + ((size_t)b * H_DIM + d) * L_DIM + l0 + tx * 4;
        *(float4*)op = r;
    }
}

extern "C" void kernel_launch(void* const* d_in, const int* in_sizes, int n_in,
                              void* d_out, int out_size, void* d_ws, size_t ws_size,
                              hipStream_t stream) {
    const float* u    = (const float*)d_in[0]; // (B,H,L)
    const float* k    = (const float*)d_in[1]; // (C,H,L) C=1
    const float* D    = (const float*)d_in[2]; // (C,H)
    const float* W    = (const float*)d_in[3]; // (H,C*H)
    const float* bias = (const float*)d_in[4]; // (H)
    float* out = (float*)d_out;
    unsigned short* g = (unsigned short*)d_ws;  // (B,H,L) bf16 intermediate, 32 MiB

    conv_gelu_mfma<<<dim3(H_DIM, L_DIM / 1024), 256, 0, stream>>>(u, k, D, g);
    pointwise_linear<<<dim3(L_DIM / 64, H_DIM / 64, B_DIM), 256, 0, stream>>>(g, W, bias, out);
}

// Round 6
// 396.934 us; speedup vs baseline: 8.3260x; 1.4356x over previous
//
#include <hip/hip_runtime.h>
#include <hip/hip_bf16.h>
#include <math.h>

#define L_DIM 4096
#define H_DIM 512
#define B_DIM 8
#define SEG 2048

typedef __attribute__((ext_vector_type(8))) short short8;
typedef __attribute__((ext_vector_type(4))) float floatx4;

__device__ __forceinline__ unsigned f2bf(float f) {
    unsigned x = __float_as_uint(f);
    return (x + 0x7fffu + ((x >> 16) & 1u)) >> 16;   // RNE, finite inputs only
}

// ---------------------------------------------------------------------------
// Stage 1 (MFMA): causal Toeplitz conv + D-skip + exact GELU.
// Round-6 change: DIAGONAL K-loop. A-frag depends only on d = l0 - m0, so we
// loop d outer and the 8 register-held accumulators t inner: one A-load
// (4x ds_read_b32, dual-parity copies) amortizes over ~5.5 MFMAs; B stays
// one ds_read_b128 per MFMA. t-bounds are wave-uniform -> scalar branches.
// ---------------------------------------------------------------------------
__global__ __launch_bounds__(256, 3) void conv_gelu_mfma(
    const float* __restrict__ u,    // (B,H,L) fp32
    const float* __restrict__ kk,   // (C=1,H,L) fp32
    const float* __restrict__ Dp,   // (H) fp32
    unsigned short* __restrict__ g) // (B,H,L) bf16 out (workspace)
{
    // kA[p] = k[L+15-p] (valid p in [16, L+15], else 0)
    // kB[p] = k[L+14-p] (valid p in [15, L+14], else 0)
    __shared__ __align__(16) unsigned short kA[4144];
    __shared__ __align__(16) unsigned short kB[4144];
    // us[b][idx] = bf16(u[b][h][ms - 32 + idx]), idx in [0,2096)
    __shared__ __align__(16) unsigned short us[8][2104];

    const int h   = blockIdx.x;
    const int Lb  = blockIdx.y << 10;        // l-chunk base
    const int tid = threadIdx.x;
    const int lane = tid & 63;
    const int w   = tid >> 6;                // wave id 0..3
    const int i   = lane & 15;               // A-row / C-col index
    const int q   = lane >> 4;               // quad
    const int b   = i & 7;                   // batch   (C-col decode)
    const int s   = i >> 3;                  // l-tile  (C-col decode)

    const float* kh = kk + (size_t)h * L_DIM;

    // ---- stage reversed k, dual copy ----
    for (int p = tid; p < 4144; p += 256) {
        int t1 = L_DIM + 15 - p;
        int t2 = L_DIM + 14 - p;
        float v1 = (t1 >= 0 && t1 < L_DIM) ? kh[t1] : 0.0f;
        float v2 = (t2 >= 0 && t2 < L_DIM) ? kh[t2] : 0.0f;
        kA[p] = (unsigned short)f2bf(v1);
        kB[p] = (unsigned short)f2bf(v2);
    }

    floatx4 acc[8];
    #pragma unroll
    for (int t = 0; t < 8; t++) acc[t] = (floatx4){0.f, 0.f, 0.f, 0.f};

    const char* kbase = (const char*)((i & 1) ? kA : kB);
    const int aconst = 2 * (L_DIM + ((i & 1) ? 15 : 14) - i + 8 * q);
    const int basew = Lb + 32 * w;           // l0(t) = basew + 128*t

    for (int seg = 0; seg < 2; seg++) {
        const int ms = seg * SEG;
        const int mstart = (seg == 0) ? -32 : SEG;
        const int segmax = ms + SEG - 32;
        if (seg == 1) {
            if (Lb + 992 < SEG) break;       // uniform per block
            __syncthreads();                 // protect us[] until seg-0 compute done
        }
        // ---- stage u segment (bf16), m in [ms-32, ms+2064) ----
        for (int e = tid * 4; e < 2096; e += 1024) {
            int m = ms - 32 + e;             // multiple of 4; fully in or out of range
            #pragma unroll
            for (int bb = 0; bb < 8; bb++) {
                float4 v = make_float4(0.f, 0.f, 0.f, 0.f);
                if (m >= 0 && m < L_DIM)
                    v = *(const float4*)(u + ((size_t)bb * H_DIM + h) * L_DIM + m);
                unsigned lo = f2bf(v.x) | (f2bf(v.y) << 16);
                unsigned hi = f2bf(v.z) | (f2bf(v.w) << 16);
                *(uint2*)&us[bb][e] = make_uint2(lo, hi);
            }
        }
        __syncthreads();

        // ---- diagonal K-loop ----
        const char* bbase = (const char*)&us[b][0] + 2 * (32 - ms + 16 * s + 8 * q);
        const char* ab = kbase + aconst;
        const int d_lo = max(0, basew - segmax);
        const int d_hi = basew + 896 - mstart;
        for (int dd = d_lo; dd <= d_hi; dd += 32) {
            const int* ap = (const int*)(ab - 2 * dd);
            union { int x[4]; short8 v; } af;
            af.x[0] = ap[0]; af.x[1] = ap[1]; af.x[2] = ap[2]; af.x[3] = ap[3];
            const int tlo = (dd + mstart - basew + 127) >> 7;   // ceil/128
            const int thi = (dd + segmax - basew) >> 7;         // floor/128
            #pragma unroll
            for (int t = 0; t < 8; t++) {
                if (t >= tlo && t <= thi) {
                    const int m0 = basew + 128 * t - dd;
                    short8 bf = *(const short8*)(bbase + 2 * m0);
                    acc[t] = __builtin_amdgcn_mfma_f32_16x16x32_bf16(af.v, bf, acc[t], 0, 0, 0);
                }
            }
        }
    }

    // ---- epilogue: skip (fp32 u) + exact GELU + bf16 store ----
    const float Dh = Dp[h];
    #pragma unroll
    for (int t = 0; t < 8; t++) {
        const int l0 = Lb + 32 * w + 128 * t;
        const int lb2 = l0 + 16 * s + 4 * q;          // C/D: row = 4q + r, col = (b,s)
        const size_t off = ((size_t)b * H_DIM + h) * L_DIM + lb2;
        float4 uv = *(const float4*)(u + off);
        float y0 = acc[t][0] + uv.x * Dh;
        float y1 = acc[t][1] + uv.y * Dh;
        float y2 = acc[t][2] + uv.z * Dh;
        float y3 = acc[t][3] + uv.w * Dh;
        const float c = 0.70710678118654752f;
        float g0 = 0.5f * y0 * (1.0f + erff(y0 * c));
        float g1 = 0.5f * y1 * (1.0f + erff(y1 * c));
        float g2 = 0.5f * y2 * (1.0f + erff(y2 * c));
        float g3 = 0.5f * y3 * (1.0f + erff(y3 * c));
        unsigned lo = f2bf(g0) | (f2bf(g1) << 16);
        unsigned hi = f2bf(g2) | (f2bf(g3) << 16);
        *(uint2*)(g + off) = make_uint2(lo, hi);
    }
}

// ---------------------------------------------------------------------------
// Stage 2 (MFMA): out[b,d,l] = sum_c W[d,c] * g[b,c,l] + bias[d], fp32 out.
// A = g^T (M=l), B = W rows (N=d), K = c.  16x16x32 bf16 MFMA, layouts
// identical to the HW-validated stage-1 usage.
// Block tile: 64 l x 256 d, K chunked by 64.  4 waves: wave w -> d quarter.
// gs2: transposed g tile, [l][36] b32 where col p = bf16x2 of c-pair (2p,2p+1)
//      -> conflict-free b32 writes, 16B-aligned b128 A-frag reads.
// ws:  [256 d][72-stride] bf16 W tile (fp32->bf16 inline), aligned b128.
// ---------------------------------------------------------------------------
__global__ __launch_bounds__(256, 3) void pointwise_mfma(
    const unsigned short* __restrict__ g,  // (B,H,L) bf16 (workspace)
    const float* __restrict__ W,           // (H,H) fp32 row-major [d][c]
    const float* __restrict__ bias,        // (H) fp32
    float* __restrict__ out)               // (B,H,L) fp32
{
    __shared__ __align__(16) unsigned gs2[64 * 36];        // 9216 B
    __shared__ __align__(16) unsigned short ws[256 * 72];  // 36864 B

    const int tid = threadIdx.x;
    const int l0 = blockIdx.x * 64;
    const int d0 = blockIdx.y * 256;
    const int bz = blockIdx.z;
    const int w  = tid >> 6;
    const int lane = tid & 63;
    const int n  = lane & 15;      // MFMA row/col lane index
    const int q  = lane >> 4;      // quad

    const int p   = tid & 31;      // c-pair column for g staging
    const int oct = tid >> 5;      // l-octet 0..7 for g staging

    floatx4 acc[4][4];
    #pragma unroll
    for (int mt = 0; mt < 4; mt++)
        #pragma unroll
        for (int nt = 0; nt < 4; nt++) acc[mt][nt] = (floatx4){0.f, 0.f, 0.f, 0.f};

    for (int c0 = 0; c0 < H_DIM; c0 += 64) {
        // ---- stage g tile (transpose-pack): thread -> (c-pair p, l-octet oct)
        {
            const unsigned short* gp = g + ((size_t)bz * H_DIM + c0 + 2 * p) * L_DIM + l0 + 8 * oct;
            uint4 va = *(const uint4*)gp;           // 8 bf16 of row c=c0+2p
            uint4 vb = *(const uint4*)(gp + L_DIM); // 8 bf16 of row c=c0+2p+1
            const unsigned* ua = (const unsigned*)&va;
            const unsigned* ub = (const unsigned*)&vb;
            #pragma unroll
            for (int e = 0; e < 4; e++) {
                unsigned w0 = (ua[e] & 0xFFFFu) | (ub[e] << 16);        // l even
                unsigned w1 = (ua[e] >> 16) | (ub[e] & 0xFFFF0000u);    // l odd
                gs2[(8 * oct + 2 * e    ) * 36 + p] = w0;
                gs2[(8 * oct + 2 * e + 1) * 36 + p] = w1;
            }
            // ---- stage W tile: thread -> d-row tid, 64 c (fp32 -> bf16)
            const float* wp = W + (size_t)(d0 + tid) * H_DIM + c0;
            #pragma unroll
            for (int gi = 0; gi < 8; gi++) {
                float4 f0 = *(const float4*)(wp + 8 * gi);
                float4 f1 = *(const float4*)(wp + 8 * gi + 4);
                unsigned o0 = f2bf(f0.x) | (f2bf(f0.y) << 16);
                unsigned o1 = f2bf(f0.z) | (f2bf(f0.w) << 16);
                unsigned o2 = f2bf(f1.x) | (f2bf(f1.y) << 16);
                unsigned o3 = f2bf(f1.z) | (f2bf(f1.w) << 16);
                *(uint4*)&ws[tid * 72 + 8 * gi] = make_uint4(o0, o1, o2, o3);
            }
        }
        __syncthreads();

        // ---- compute: 2 K-steps of 32, 16 MFMAs each per wave
        #pragma unroll
        for (int ks = 0; ks < 2; ks++) {
            short8 bfr[4];
            #pragma unroll
            for (int nt = 0; nt < 4; nt++)
                bfr[nt] = *(const short8*)&ws[(64 * w + 16 * nt + n) * 72 + 32 * ks + 8 * q];
            #pragma unroll
            for (int mt = 0; mt < 4; mt++) {
                union { uint4 u4; short8 v; } af;
                af.u4 = *(const uint4*)&gs2[(16 * mt + n) * 36 + 16 * ks + 4 * q];
                #pragma unroll
                for (int nt = 0; nt < 4; nt++)
                    acc[mt][nt] = __builtin_amdgcn_mfma_f32_16x16x32_bf16(af.v, bfr[nt], acc[mt][nt], 0, 0, 0);
            }
        }
        __syncthreads();
    }

    // ---- epilogue: bias + coalesced float4 stores (4 consecutive l per lane)
    #pragma unroll
    for (int nt = 0; nt < 4; nt++) {
        const int d = d0 + 64 * w + 16 * nt + n;
        const float bb = bias[d];
        float* obase = out + ((size_t)bz * H_DIM + d) * L_DIM + l0 + 4 * q;
        #pragma unroll
        for (int mt = 0; mt < 4; mt++) {
            float4 r = make_float4(acc[mt][nt][0] + bb, acc[mt][nt][1] + bb,
                                   acc[mt][nt][2] + bb, acc[mt][nt][3] + bb);
            *(float4*)(obase + 16 * mt) = r;
        }
    }
}

extern "C" void kernel_launch(void* const* d_in, const int* in_sizes, int n_in,
                              void* d_out, int out_size, void* d_ws, size_t ws_size,
                              hipStream_t stream) {
    const float* u    = (const float*)d_in[0]; // (B,H,L)
    const float* k    = (const float*)d_in[1]; // (C,H,L) C=1
    const float* D    = (const float*)d_in[2]; // (C,H)
    const float* W    = (const float*)d_in[3]; // (H,C*H)
    const float* bias = (const float*)d_in[4]; // (H)
    float* out = (float*)d_out;
    unsigned short* g = (unsigned short*)d_ws;  // (B,H,L) bf16 intermediate, 32 MiB

    conv_gelu_mfma<<<dim3(H_DIM, L_DIM / 1024), 256, 0, stream>>>(u, k, D, g);
    pointwise_mfma<<<dim3(L_DIM / 64, H_DIM / 256, B_DIM), 256, 0, stream>>>(g, W, bias, out);
}

// Round 7
// 356.754 us; speedup vs baseline: 9.2638x; 1.1126x over previous
//
#include <hip/hip_runtime.h>
#include <hip/hip_bf16.h>
#include <math.h>

#define L_DIM 4096
#define H_DIM 512
#define B_DIM 8
#define SEG 2048

typedef __attribute__((ext_vector_type(8))) short short8;
typedef __attribute__((ext_vector_type(4))) float floatx4;

__device__ __forceinline__ unsigned f2bf(float f) {
    unsigned x = __float_as_uint(f);
    return (x + 0x7fffu + ((x >> 16) & 1u)) >> 16;   // RNE, finite inputs only
}

// ---------------------------------------------------------------------------
// Stage 1 (MFMA): causal Toeplitz conv + D-skip + exact GELU.
// Diagonal K-loop: A-frag depends only on d = l0 - m0; loop d outer, the 8
// register-held accumulators t inner -> one A-load amortizes over ~5.5 MFMAs.
// UNCHANGED from round 6 (HW-verified, 236 us).
// ---------------------------------------------------------------------------
__global__ __launch_bounds__(256, 3) void conv_gelu_mfma(
    const float* __restrict__ u,    // (B,H,L) fp32
    const float* __restrict__ kk,   // (C=1,H,L) fp32
    const float* __restrict__ Dp,   // (H) fp32
    unsigned short* __restrict__ g) // (B,H,L) bf16 out (workspace)
{
    __shared__ __align__(16) unsigned short kA[4144];
    __shared__ __align__(16) unsigned short kB[4144];
    __shared__ __align__(16) unsigned short us[8][2104];

    const int h   = blockIdx.x;
    const int Lb  = blockIdx.y << 10;        // l-chunk base
    const int tid = threadIdx.x;
    const int lane = tid & 63;
    const int w   = tid >> 6;                // wave id 0..3
    const int i   = lane & 15;               // A-row / C-col index
    const int q   = lane >> 4;               // quad
    const int b   = i & 7;                   // batch   (C-col decode)
    const int s   = i >> 3;                  // l-tile  (C-col decode)

    const float* kh = kk + (size_t)h * L_DIM;

    for (int p = tid; p < 4144; p += 256) {
        int t1 = L_DIM + 15 - p;
        int t2 = L_DIM + 14 - p;
        float v1 = (t1 >= 0 && t1 < L_DIM) ? kh[t1] : 0.0f;
        float v2 = (t2 >= 0 && t2 < L_DIM) ? kh[t2] : 0.0f;
        kA[p] = (unsigned short)f2bf(v1);
        kB[p] = (unsigned short)f2bf(v2);
    }

    floatx4 acc[8];
    #pragma unroll
    for (int t = 0; t < 8; t++) acc[t] = (floatx4){0.f, 0.f, 0.f, 0.f};

    const char* kbase = (const char*)((i & 1) ? kA : kB);
    const int aconst = 2 * (L_DIM + ((i & 1) ? 15 : 14) - i + 8 * q);
    const int basew = Lb + 32 * w;           // l0(t) = basew + 128*t

    for (int seg = 0; seg < 2; seg++) {
        const int ms = seg * SEG;
        const int mstart = (seg == 0) ? -32 : SEG;
        const int segmax = ms + SEG - 32;
        if (seg == 1) {
            if (Lb + 992 < SEG) break;       // uniform per block
            __syncthreads();                 // protect us[] until seg-0 compute done
        }
        for (int e = tid * 4; e < 2096; e += 1024) {
            int m = ms - 32 + e;
            #pragma unroll
            for (int bb = 0; bb < 8; bb++) {
                float4 v = make_float4(0.f, 0.f, 0.f, 0.f);
                if (m >= 0 && m < L_DIM)
                    v = *(const float4*)(u + ((size_t)bb * H_DIM + h) * L_DIM + m);
                unsigned lo = f2bf(v.x) | (f2bf(v.y) << 16);
                unsigned hi = f2bf(v.z) | (f2bf(v.w) << 16);
                *(uint2*)&us[bb][e] = make_uint2(lo, hi);
            }
        }
        __syncthreads();

        const char* bbase = (const char*)&us[b][0] + 2 * (32 - ms + 16 * s + 8 * q);
        const char* ab = kbase + aconst;
        const int d_lo = max(0, basew - segmax);
        const int d_hi = basew + 896 - mstart;
        for (int dd = d_lo; dd <= d_hi; dd += 32) {
            const int* ap = (const int*)(ab - 2 * dd);
            union { int x[4]; short8 v; } af;
            af.x[0] = ap[0]; af.x[1] = ap[1]; af.x[2] = ap[2]; af.x[3] = ap[3];
            const int tlo = (dd + mstart - basew + 127) >> 7;   // ceil/128
            const int thi = (dd + segmax - basew) >> 7;         // floor/128
            #pragma unroll
            for (int t = 0; t < 8; t++) {
                if (t >= tlo && t <= thi) {
                    const int m0 = basew + 128 * t - dd;
                    short8 bf = *(const short8*)(bbase + 2 * m0);
                    acc[t] = __builtin_amdgcn_mfma_f32_16x16x32_bf16(af.v, bf, acc[t], 0, 0, 0);
                }
            }
        }
    }

    const float Dh = Dp[h];
    #pragma unroll
    for (int t = 0; t < 8; t++) {
        const int l0 = Lb + 32 * w + 128 * t;
        const int lb2 = l0 + 16 * s + 4 * q;          // C/D: row = 4q + r, col = (b,s)
        const size_t off = ((size_t)b * H_DIM + h) * L_DIM + lb2;
        float4 uv = *(const float4*)(u + off);
        float y0 = acc[t][0] + uv.x * Dh;
        float y1 = acc[t][1] + uv.y * Dh;
        float y2 = acc[t][2] + uv.z * Dh;
        float y3 = acc[t][3] + uv.w * Dh;
        const float c = 0.70710678118654752f;
        float g0 = 0.5f * y0 * (1.0f + erff(y0 * c));
        float g1 = 0.5f * y1 * (1.0f + erff(y1 * c));
        float g2 = 0.5f * y2 * (1.0f + erff(y2 * c));
        float g3 = 0.5f * y3 * (1.0f + erff(y3 * c));
        unsigned lo = f2bf(g0) | (f2bf(g1) << 16);
        unsigned hi = f2bf(g2) | (f2bf(g3) << 16);
        *(uint2*)(g + off) = make_uint2(lo, hi);
    }
}

// ---------------------------------------------------------------------------
// Stage 2 (MFMA v2): out[b,d,l] = sum_c W[d,c]*g[b,c,l] + bias[d], fp32 out.
// Round-7 changes: (1) tile 128 l x 256 d (512 blocks, 2/CU) — 4x compute
// per barrier, half the W re-fetch; (2) COALESCED W staging: thread
// (quarter=tid&3, rb=tid>>2) reads 16 consecutive floats of rows rb+64*gg —
// full cache-line utilization (was: 1 row/thread, 16B-of-64B lines, ~2 GB L2
// traffic -> the 150 us). Fragment logic identical to the round-6 pass.
// ---------------------------------------------------------------------------
__global__ __launch_bounds__(256, 2) void pointwise_mfma(
    const unsigned short* __restrict__ g,  // (B,H,L) bf16 (workspace)
    const float* __restrict__ W,           // (H,H) fp32 row-major [d][c]
    const float* __restrict__ bias,        // (H) fp32
    float* __restrict__ out)               // (B,H,L) fp32
{
    __shared__ __align__(16) unsigned gs2[128 * 36];        // 18432 B
    __shared__ __align__(16) unsigned short ws[256 * 72];   // 36864 B

    const int tid = threadIdx.x;
    const int l0 = blockIdx.x * 128;
    const int d0 = blockIdx.y * 256;
    const int bz = blockIdx.z;
    const int w  = tid >> 6;
    const int lane = tid & 63;
    const int n  = lane & 15;      // MFMA row/col lane index
    const int q  = lane >> 4;      // quad

    const int p   = tid & 31;      // c-pair column for g staging
    const int oct = tid >> 5;      // l-16-group 0..7 for g staging

    const int quarter = tid & 3;   // c-quarter for W staging
    const int rb      = tid >> 2;  // d-row base 0..63 for W staging

    floatx4 acc[8][4];
    #pragma unroll
    for (int mt = 0; mt < 8; mt++)
        #pragma unroll
        for (int nt = 0; nt < 4; nt++) acc[mt][nt] = (floatx4){0.f, 0.f, 0.f, 0.f};

    for (int c0 = 0; c0 < H_DIM; c0 += 64) {
        // ---- stage g tile (transpose-pack): rows c0+2p/+1, l = l0+16*oct+0..15
        {
            const unsigned short* gp = g + ((size_t)bz * H_DIM + c0 + 2 * p) * L_DIM + l0 + 16 * oct;
            uint4 va0 = *(const uint4*)gp;
            uint4 va1 = *(const uint4*)(gp + 8);
            uint4 vb0 = *(const uint4*)(gp + L_DIM);
            uint4 vb1 = *(const uint4*)(gp + L_DIM + 8);
            #pragma unroll
            for (int half = 0; half < 2; half++) {
                const unsigned* ua = (const unsigned*)(half ? &va1 : &va0);
                const unsigned* ub = (const unsigned*)(half ? &vb1 : &vb0);
                #pragma unroll
                for (int e = 0; e < 4; e++) {
                    unsigned w0 = (ua[e] & 0xFFFFu) | (ub[e] << 16);        // l even
                    unsigned w1 = (ua[e] >> 16) | (ub[e] & 0xFFFF0000u);    // l odd
                    const int lrow = 16 * oct + 8 * half + 2 * e;
                    gs2[lrow * 36 + p] = w0;
                    gs2[(lrow + 1) * 36 + p] = w1;
                }
            }
        }
        // ---- stage W tile, coalesced: rows rb+64*gg, c = 16*quarter..+15
        {
            #pragma unroll
            for (int gg = 0; gg < 4; gg++) {
                const int row = rb + 64 * gg;
                const float* wp = W + (size_t)(d0 + row) * H_DIM + c0 + 16 * quarter;
                float4 f0 = ((const float4*)wp)[0];
                float4 f1 = ((const float4*)wp)[1];
                float4 f2 = ((const float4*)wp)[2];
                float4 f3 = ((const float4*)wp)[3];
                unsigned o0 = f2bf(f0.x) | (f2bf(f0.y) << 16);
                unsigned o1 = f2bf(f0.z) | (f2bf(f0.w) << 16);
                unsigned o2 = f2bf(f1.x) | (f2bf(f1.y) << 16);
                unsigned o3 = f2bf(f1.z) | (f2bf(f1.w) << 16);
                unsigned o4 = f2bf(f2.x) | (f2bf(f2.y) << 16);
                unsigned o5 = f2bf(f2.z) | (f2bf(f2.w) << 16);
                unsigned o6 = f2bf(f3.x) | (f2bf(f3.y) << 16);
                unsigned o7 = f2bf(f3.z) | (f2bf(f3.w) << 16);
                *(uint4*)&ws[row * 72 + 16 * quarter]     = make_uint4(o0, o1, o2, o3);
                *(uint4*)&ws[row * 72 + 16 * quarter + 8] = make_uint4(o4, o5, o6, o7);
            }
        }
        __syncthreads();

        // ---- compute: 2 K-steps of 32; per wave 8 mt x 4 nt MFMAs per step
        #pragma unroll
        for (int ks = 0; ks < 2; ks++) {
            short8 bfr[4];
            #pragma unroll
            for (int nt = 0; nt < 4; nt++)
                bfr[nt] = *(const short8*)&ws[(64 * w + 16 * nt + n) * 72 + 32 * ks + 8 * q];
            #pragma unroll
            for (int mt = 0; mt < 8; mt++) {
                union { uint4 u4; short8 v; } af;
                af.u4 = *(const uint4*)&gs2[(16 * mt + n) * 36 + 16 * ks + 4 * q];
                #pragma unroll
                for (int nt = 0; nt < 4; nt++)
                    acc[mt][nt] = __builtin_amdgcn_mfma_f32_16x16x32_bf16(af.v, bfr[nt], acc[mt][nt], 0, 0, 0);
            }
        }
        __syncthreads();
    }

    // ---- epilogue: bias + coalesced float4 stores (4 consecutive l per lane)
    #pragma unroll
    for (int nt = 0; nt < 4; nt++) {
        const int d = d0 + 64 * w + 16 * nt + n;
        const float bb = bias[d];
        float* obase = out + ((size_t)bz * H_DIM + d) * L_DIM + l0 + 4 * q;
        #pragma unroll
        for (int mt = 0; mt < 8; mt++) {
            float4 r = make_float4(acc[mt][nt][0] + bb, acc[mt][nt][1] + bb,
                                   acc[mt][nt][2] + bb, acc[mt][nt][3] + bb);
            *(float4*)(obase + 16 * mt) = r;
        }
    }
}

extern "C" void kernel_launch(void* const* d_in, const int* in_sizes, int n_in,
                              void* d_out, int out_size, void* d_ws, size_t ws_size,
                              hipStream_t stream) {
    const float* u    = (const float*)d_in[0]; // (B,H,L)
    const float* k    = (const float*)d_in[1]; // (C,H,L) C=1
    const float* D    = (const float*)d_in[2]; // (C,H)
    const float* W    = (const float*)d_in[3]; // (H,C*H)
    const float* bias = (const float*)d_in[4]; // (H)
    float* out = (float*)d_out;
    unsigned short* g = (unsigned short*)d_ws;  // (B,H,L) bf16 intermediate, 32 MiB

    conv_gelu_mfma<<<dim3(H_DIM, L_DIM / 1024), 256, 0, stream>>>(u, k, D, g);
    pointwise_mfma<<<dim3(L_DIM / 128, H_DIM / 256, B_DIM), 256, 0, stream>>>(g, W, bias, out);
}